// Round 2
// baseline (1507.675 us; speedup 1.0000x reference)
//
#include <hip/hip_runtime.h>
#include <hip/hip_bf16.h>

#define B_ 16
#define S_ 2048
#define C_ 512
#define H_ 8192

#define LAMBDA_INIT_F 0.3555090675909693f
#define ONE_M_LI_F    0.6444909324090307f
#define SCALE_F       0.14865088937534013f

using bf16x8 = __attribute__((ext_vector_type(8))) short;
using f32x4  = __attribute__((ext_vector_type(4))) float;

__device__ __forceinline__ float b2f(ushort u) {
  union { unsigned u; float f; } x; x.u = ((unsigned)u) << 16; return x.f;
}
__device__ __forceinline__ ushort f2b(float f) {
  union { float f; unsigned u; } x; x.f = f;
  unsigned r = x.u + 0x7fffu + ((x.u >> 16) & 1u);
  return (ushort)(r >> 16);
}

__device__ __forceinline__ void load_lds16(const void* g, void* s) {
  __builtin_amdgcn_global_load_lds((const __attribute__((address_space(1))) void*)g,
                                   (__attribute__((address_space(3))) void*)s,
                                   16, 0, 0);
}

// ---------------- block-wide reductions (256 threads = 4 waves) ----------------
__device__ __forceinline__ float block_sum(float v, float* red) {
#pragma unroll
  for (int o = 32; o > 0; o >>= 1) v += __shfl_down(v, o, 64);
  __syncthreads();
  if ((threadIdx.x & 63) == 0) red[threadIdx.x >> 6] = v;
  __syncthreads();
  return red[0] + red[1] + red[2] + red[3];
}
__device__ __forceinline__ float block_max(float v, float* red) {
#pragma unroll
  for (int o = 32; o > 0; o >>= 1) v = fmaxf(v, __shfl_down(v, o, 64));
  __syncthreads();
  if ((threadIdx.x & 63) == 0) red[threadIdx.x >> 6] = v;
  __syncthreads();
  return fmaxf(fmaxf(red[0], red[1]), fmaxf(red[2], red[3]));
}

// ---- NT GEMM: C[m,n] = sum_k A[m,k]*Bt[n,k]  (bf16 in, f32 acc), 128x128 tile, BK=32
// EPI 0: f32 store acc*alpha
// EPI 1: bf16 store acc+bias[n]
// EPI 2: bf16 store gelu(acc+bias[n])
// EPI 3: bf16 store acc*alpha
// EPI 4: f32 store acc (+bias[n] if bias) (+C_old if accflag)
template <int EPI>
__global__ __launch_bounds__(256, 2) void gemm_nt(
    const ushort* __restrict__ Aall, const ushort* __restrict__ Ball,
    void* __restrict__ Call, const float* __restrict__ bias,
    int K, int lda, int ldb, int ldc,
    long sA, long sB, long sC, float alpha, int accflag)
{
  __shared__ ushort lA[4096];  // 128 rows x 32 k
  __shared__ ushort lB[4096];
  const int t = threadIdx.x;
  const int m0 = blockIdx.x * 128, n0 = blockIdx.y * 128;
  const ushort* A  = Aall + (size_t)blockIdx.z * sA;
  const ushort* Bt = Ball + (size_t)blockIdx.z * sB;
  const int lane = t & 63;
  const int wave = t >> 6;
  const int wm = (wave >> 1) * 64, wn = (wave & 1) * 64;
  const int fr = lane & 15, kh = lane >> 4;
  f32x4 acc[4][4] = {};
  const int srow = t >> 2;          // 0..63
  const int scol = (t & 3) * 8;     // 0,8,16,24
  const size_t ar0 = (size_t)(m0 + srow) * lda + scol;
  const size_t ar1 = (size_t)(m0 + 64 + srow) * lda + scol;
  const size_t br0 = (size_t)(n0 + srow) * ldb + scol;
  const size_t br1 = (size_t)(n0 + 64 + srow) * ldb + scol;
  const int wbase = wave * 512;     // wave-uniform LDS chunk (elements)

  for (int k0 = 0; k0 < K; k0 += 32) {
    __syncthreads();  // previous tile's ds_reads done before overwrite
    load_lds16(A + ar0 + k0,  &lA[wbase]);
    load_lds16(A + ar1 + k0,  &lA[2048 + wbase]);
    load_lds16(Bt + br0 + k0, &lB[wbase]);
    load_lds16(Bt + br1 + k0, &lB[2048 + wbase]);
    __syncthreads();  // __syncthreads drains vmcnt: tile ready
    bf16x8 af[4], bg[4];
#pragma unroll
    for (int i = 0; i < 4; ++i)
      af[i] = *(const bf16x8*)&lA[(wm + i * 16 + fr) * 32 + kh * 8];
#pragma unroll
    for (int j = 0; j < 4; ++j)
      bg[j] = *(const bf16x8*)&lB[(wn + j * 16 + fr) * 32 + kh * 8];
#pragma unroll
    for (int i = 0; i < 4; ++i)
#pragma unroll
      for (int j = 0; j < 4; ++j)
        acc[i][j] = __builtin_amdgcn_mfma_f32_16x16x32_bf16(af[i], bg[j], acc[i][j], 0, 0, 0);
  }

  const int r0 = kh * 4;  // C/D: col = lane&15, row = (lane>>4)*4 + reg  [m89-verified]
  if constexpr (EPI == 0 || EPI == 4) {
    float* C = (float*)Call + (size_t)blockIdx.z * sC;
#pragma unroll
    for (int i = 0; i < 4; ++i)
#pragma unroll
      for (int j = 0; j < 4; ++j) {
        const int gr = m0 + wm + i * 16 + r0;
        const int gc = n0 + wn + j * 16 + fr;
        float bb = 0.f;
        if constexpr (EPI == 4) { if (bias) bb = bias[gc]; }
#pragma unroll
        for (int r = 0; r < 4; ++r) {
          const size_t idx = (size_t)(gr + r) * ldc + gc;
          float v;
          if constexpr (EPI == 0) v = acc[i][j][r] * alpha;
          else {
            v = acc[i][j][r] + bb;
            if (accflag) v += C[idx];
          }
          C[idx] = v;
        }
      }
  } else {
    ushort* C = (ushort*)Call + (size_t)blockIdx.z * sC;
#pragma unroll
    for (int i = 0; i < 4; ++i)
#pragma unroll
      for (int j = 0; j < 4; ++j) {
        const int gr = m0 + wm + i * 16 + r0;
        const int gc = n0 + wn + j * 16 + fr;
        const float bb = (EPI == 3) ? 0.f : bias[gc];
#pragma unroll
        for (int r = 0; r < 4; ++r) {
          float v = acc[i][j][r] + bb;
          if constexpr (EPI == 3) v = acc[i][j][r] * alpha;
          if constexpr (EPI == 2) v = 0.5f * v * (1.f + erff(v * 0.7071067811865475f));
          C[(size_t)(gr + r) * ldc + gc] = f2b(v);
        }
      }
  }
}

// ---------------- elementwise / transpose kernels ----------------

__global__ __launch_bounds__(256) void k_rms_part(const float* __restrict__ x, float* __restrict__ part) {
  const int c = blockIdx.x * 256 + threadIdx.x;   // grid.x = 2
  const int sl = blockIdx.y;                      // 8 slices of 256
  const int b = blockIdx.z;
  const float* p = x + (size_t)b * S_ * C_ + c;
  const int s0 = sl * 256;
  float s = 0.f;
  for (int i = 0; i < 256; ++i) { float v = p[(size_t)(s0 + i) * C_]; s += v * v; }
  part[((size_t)b * C_ + c) * 8 + sl] = s;
}
__global__ __launch_bounds__(256) void k_rms_fin(const float* __restrict__ part, float* __restrict__ rms1) {
  const int i = blockIdx.x * 256 + threadIdx.x;  // 8192
  const float* p = part + (size_t)i * 8;
  float s = 0.f;
#pragma unroll
  for (int j = 0; j < 8; ++j) s += p[j];
  rms1[i] = rsqrtf(s * (1.f / S_) + 1e-8f);
}

// x [B,S,C] -> xT bf16 [B,C,S] and aT = x*rms1[b,c]*w[s]
__global__ __launch_bounds__(256) void k_trans_norm(const float* __restrict__ x, const float* __restrict__ rms1,
                                                    const float* __restrict__ w,
                                                    ushort* __restrict__ aT, ushort* __restrict__ xT) {
  __shared__ float tile[32][33];
  const int s0 = blockIdx.x * 32, c0 = blockIdx.y * 32, b = blockIdx.z;
  const int tx = threadIdx.x, ty = threadIdx.y;
  const float* xb = x + (size_t)b * S_ * C_;
#pragma unroll
  for (int r = 0; r < 4; ++r) {
    const int s = ty + 8 * r;
    tile[s][tx] = xb[(size_t)(s0 + s) * C_ + c0 + tx];
  }
  __syncthreads();
#pragma unroll
  for (int r = 0; r < 4; ++r) {
    const int c = ty + 8 * r;
    const float v = tile[tx][c];                       // x[s0+tx][c0+c]
    const float rm = rms1[b * C_ + c0 + c];
    const size_t o = ((size_t)b * C_ + c0 + c) * S_ + s0 + tx;
    xT[o] = f2b(v);
    aT[o] = f2b(v * rm * w[s0 + tx]);
  }
}

// f32 W[k, n] (row-stride Ndstride) cols [n_base, n_base+grid.y*32) -> bf16 WT[n_local, k]
__global__ __launch_bounds__(256) void k_wtrans(const float* __restrict__ W, ushort* __restrict__ WT,
                                                int Kd, int Ndstride, int n_base) {
  __shared__ float tile[32][33];
  const int k0 = blockIdx.x * 32, n0 = blockIdx.y * 32;
  const int tx = threadIdx.x, ty = threadIdx.y;
#pragma unroll
  for (int r = 0; r < 4; ++r) {
    const int k = ty + 8 * r;
    tile[k][tx] = W[(size_t)(k0 + k) * Ndstride + n_base + n0 + tx];
  }
  __syncthreads();
#pragma unroll
  for (int r = 0; r < 4; ++r) {
    const int n = ty + 8 * r;
    WT[(size_t)(n0 + n) * Kd + k0 + tx] = f2b(tile[tx][n]);
  }
}

// bf16 [Z,R,CL] -> [Z,CL,R]
__global__ __launch_bounds__(256) void k_bt(const ushort* __restrict__ in, ushort* __restrict__ out, int R, int CL) {
  __shared__ ushort tile[32][33];
  const int r0 = blockIdx.x * 32, c0 = blockIdx.y * 32;
  const size_t zb = (size_t)blockIdx.z * R * CL;
  const int tx = threadIdx.x, ty = threadIdx.y;
#pragma unroll
  for (int r = 0; r < 4; ++r) {
    const int rr = ty + 8 * r;
    tile[rr][tx] = in[zb + (size_t)(r0 + rr) * CL + c0 + tx];
  }
  __syncthreads();
#pragma unroll
  for (int r = 0; r < 4; ++r) {
    const int cc = ty + 8 * r;
    out[zb + (size_t)(c0 + cc) * R + r0 + tx] = tile[tx][cc];
  }
}

// moving-average-5 trend along contiguous seq axis (replicate pad == clamp)
__device__ __forceinline__ float trend5(const ushort* p, int s) {
  float sum = 0.f;
#pragma unroll
  for (int d = -2; d <= 2; ++d) {
    int ss = s + d; ss = ss < 0 ? 0 : (ss > S_ - 1 ? S_ - 1 : ss);
    sum += b2f(p[ss]);
  }
  return sum * 0.2f;
}
__global__ __launch_bounds__(256) void k_dtrend(const ushort* __restrict__ aT, ushort* __restrict__ trT) {
  const size_t i = (size_t)blockIdx.x * 256 + threadIdx.x;
  const int s = (int)(i & (S_ - 1));
  trT[i] = f2b(trend5(aT + (i - s), s));
}
__global__ __launch_bounds__(256) void k_dseason(const ushort* __restrict__ aT, ushort* __restrict__ seT) {
  const size_t i = (size_t)blockIdx.x * 256 + threadIdx.x;
  const int s = (int)(i & (S_ - 1));
  const ushort* p = aT + (i - s);
  seT[i] = f2b(b2f(p[s]) - trend5(p, s));
}

__global__ __launch_bounds__(256) void k_lambda(const float* __restrict__ lq1, const float* __restrict__ lk1,
                                                const float* __restrict__ lq2, const float* __restrict__ lk2,
                                                float* __restrict__ lam) {
  __shared__ float r1[4], r2[4];
  const int t = threadIdx.x;
  float s1 = 0.f, s2 = 0.f;
  for (int i = t; i < S_; i += 256) { s1 += lq1[i] * lk1[i]; s2 += lq2[i] * lk2[i]; }
#pragma unroll
  for (int o = 32; o > 0; o >>= 1) { s1 += __shfl_down(s1, o, 64); s2 += __shfl_down(s2, o, 64); }
  if ((t & 63) == 0) { r1[t >> 6] = s1; r2[t >> 6] = s2; }
  __syncthreads();
  if (t == 0) {
    const float a = r1[0] + r1[1] + r1[2] + r1[3];
    const float b = r2[0] + r2[1] + r2[2] + r2[3];
    *lam = expf(a) - expf(b) + LAMBDA_INIT_F;
  }
}

// d = softmax(a1) - lam*softmax(a2), rows of 512, bf16 out
__global__ __launch_bounds__(256) void k_softmax(const float* __restrict__ a1, const float* __restrict__ a2,
                                                 const float* __restrict__ lamp, ushort* __restrict__ dm) {
  __shared__ float red[4];
  const size_t row = blockIdx.x;
  const float* p1 = a1 + row * 512;
  const float* p2 = a2 + row * 512;
  const int t = threadIdx.x;
  const float v1a = p1[t], v1b = p1[t + 256];
  const float v2a = p2[t], v2b = p2[t + 256];
  const float m1 = block_max(fmaxf(v1a, v1b), red);
  const float m2 = block_max(fmaxf(v2a, v2b), red);
  const float e1a = expf(v1a - m1), e1b = expf(v1b - m1);
  const float e2a = expf(v2a - m2), e2b = expf(v2b - m2);
  const float s1 = block_sum(e1a + e1b, red);
  const float s2 = block_sum(e2a + e2b, red);
  const float i1 = 1.f / s1, i2 = (*lamp) / s2;
  ushort* o = dm + row * 512;
  o[t]       = f2b(e1a * i1 - e2a * i2);
  o[t + 256] = f2b(e1b * i1 - e2b * i2);
}

// P(bf16) row -> rmsnorm*norm_w*(1-li) -> attn bf16; x2=xT+attn -> rmsnorm*ln_ff_w -> h bf16
__global__ __launch_bounds__(256) void k_postattn(const ushort* __restrict__ P, const ushort* __restrict__ xT,
                                                  const float* __restrict__ norm_w, const float* __restrict__ ln_ff_w,
                                                  ushort* __restrict__ attn, ushort* __restrict__ h) {
  __shared__ float red[4];
  const size_t row = blockIdx.x;  // b*C + c
  const ushort* p = P + row * S_;
  const int t = threadIdx.x;
  float v[8]; float ss = 0.f;
#pragma unroll
  for (int i = 0; i < 8; ++i) { v[i] = b2f(p[t + 256 * i]); ss += v[i] * v[i]; }
  ss = block_sum(ss, red);
  const float inv = rsqrtf(ss * (1.f / S_) + 1e-8f);
  const ushort* xr = xT + row * S_;
  ushort* ar = attn + row * S_;
  float x2[8]; float ss2 = 0.f;
#pragma unroll
  for (int i = 0; i < 8; ++i) {
    const int s = t + 256 * i;
    const float at = v[i] * inv * norm_w[s] * ONE_M_LI_F;
    ar[s] = f2b(at);
    const float xx = b2f(xr[s]) + at;
    x2[i] = xx; ss2 += xx * xx;
  }
  ss2 = block_sum(ss2, red);
  const float inv2 = rsqrtf(ss2 * (1.f / S_) + 1e-8f);
  ushort* hr = h + row * S_;
#pragma unroll
  for (int i = 0; i < 8; ++i) { const int s = t + 256 * i; hr[s] = f2b(x2[i] * inv2 * ln_ff_w[s]); }
}

// sumT = attn(bf16) + ffoF(f32), both [B,C,S]
__global__ __launch_bounds__(256) void k_combine(const ushort* __restrict__ attn, const float* __restrict__ ffoF,
                                                 ushort* __restrict__ sumT) {
  const size_t base = (size_t)blockIdx.x * 2048 + threadIdx.x * 8;
#pragma unroll
  for (int i = 0; i < 8; ++i) sumT[base + i] = f2b(b2f(attn[base + i]) + ffoF[base + i]);
}

// out[b,s,c] = x[b,s,c] + sumT[b,c,s]
__global__ __launch_bounds__(256) void k_final(const float* __restrict__ x, const ushort* __restrict__ sumT,
                                               float* __restrict__ out) {
  __shared__ float tile[32][33];
  const int s0 = blockIdx.x * 32, c0 = blockIdx.y * 32, b = blockIdx.z;
  const int tx = threadIdx.x, ty = threadIdx.y;
#pragma unroll
  for (int r = 0; r < 4; ++r) {
    const int c = ty + 8 * r;
    tile[c][tx] = b2f(sumT[((size_t)b * C_ + c0 + c) * S_ + s0 + tx]);
  }
  __syncthreads();
#pragma unroll
  for (int r = 0; r < 4; ++r) {
    const int s = ty + 8 * r;
    const size_t o = ((size_t)b * S_ + s0 + s) * C_ + c0 + tx;
    out[o] = x[o] + tile[tx][s];
  }
}

__global__ void k_probe(float* out, float v) { out[0] = v; }

// ---------------- launch ----------------
extern "C" void kernel_launch(void* const* d_in, const int* in_sizes, int n_in,
                              void* d_out, int out_size, void* d_ws, size_t ws_size,
                              hipStream_t stream) {
  const float* x       = (const float*)d_in[0];
  const float* ln_attn = (const float*)d_in[1];
  const float* q12_w   = (const float*)d_in[2];
  const float* q12_b   = (const float*)d_in[3];
  const float* k12_w   = (const float*)d_in[4];
  const float* k12_b   = (const float*)d_in[5];
  const float* v_w     = (const float*)d_in[6];
  const float* v_b     = (const float*)d_in[7];
  const float* lq1     = (const float*)d_in[8];
  const float* lk1     = (const float*)d_in[9];
  const float* lq2     = (const float*)d_in[10];
  const float* lk2     = (const float*)d_in[11];
  const float* norm_w  = (const float*)d_in[12];
  const float* ln_ff   = (const float*)d_in[13];
  const float* ff_w1   = (const float*)d_in[14];
  const float* ff_b1   = (const float*)d_in[15];
  const float* ff_w2   = (const float*)d_in[16];
  const float* ff_b2   = (const float*)d_in[17];
  float* out = (float*)d_out;

  // arena needs ~176 MiB; if short, report ws_size (in MB) through out[0]
  if (ws_size < 184844544ull) {
    k_probe<<<1, 1, 0, stream>>>(out, (float)(ws_size >> 20));
    return;
  }

  char* ws = (char*)d_ws;
  // slot map (liveness-packed):
  ushort* xT    = (ushort*)(ws + 0);          // S0: xT (P1-postattn) / sumT (end)
  ushort* sumT  = (ushort*)(ws + 0);
  ushort* aT    = (ushort*)(ws + 33554432);   // S1: aT / k1k2 / Pm
  ushort* Kh    = (ushort*)(ws + 33554432);
  ushort* Pm    = (ushort*)(ws + 33554432);
  ushort* VT    = (ushort*)(ws + 67108864);   // S2: VT / hbuf
  ushort* hbuf  = (ushort*)(ws + 67108864);
  ushort* trT   = (ushort*)(ws + 100663296);  // S3: trT / seT / attn
  ushort* seT   = (ushort*)(ws + 100663296);
  ushort* attn  = (ushort*)(ws + 100663296);
  ushort* Vm    = (ushort*)(ws + 134217728);  // S4: Vm / a1+a2 / H1c
  float*  a1    = (float*) (ws + 134217728);
  float*  a2    = (float*) (ws + 150994944);
  ushort* H1c   = (ushort*)(ws + 134217728);
  ushort* wslot = (ushort*)(ws + 167772160);  // S5 (16.78M): vwT/q12T/k12Th/dmat/ff1Tc + ff2Tc
  ushort* wslot2= (ushort*)(ws + 176160768);  //   second 8.39M half (ff2Tc)
  ushort* dmat  = (ushort*)(ws + 167772160);
  float*  part  = (float*) (ws + 184549376);
  float*  rms1  = (float*) (ws + 184811520);
  float*  lamp  = (float*) (ws + 184844288);
  // d_out doubles as scratch: Qm bf16 [8192,4096] (P_proj..scores), then ffoF f32 [8192,2048]
  ushort* Qm    = (ushort*)d_out;
  float*  ffoF  = (float*)d_out;

  const dim3 blk256(256), blkT(32, 8);

  // seq-axis rmsnorm + transpose
  k_rms_part<<<dim3(2, 8, B_), blk256, 0, stream>>>(x, part);
  k_rms_fin<<<dim3(32), blk256, 0, stream>>>(part, rms1);
  k_trans_norm<<<dim3(64, 16, B_), blkT, 0, stream>>>(x, rms1, ln_attn, aT, xT);

  // V path: Vm = aT @ v_w + b, then VT = Vm^T per batch
  k_wtrans<<<dim3(64, 64), blkT, 0, stream>>>(v_w, wslot, 2048, 2048, 0);
  gemm_nt<1><<<dim3(64, 16), blk256, 0, stream>>>(aT, wslot, Vm, v_b, 2048, 2048, 2048, 2048, 0, 0, 0, 1.f, 0);
  k_bt<<<dim3(16, 64, B_), blkT, 0, stream>>>(Vm, VT, 512, 2048);

  // trend -> Q (full 2E columns, into d_out)
  k_dtrend<<<dim3(65536), blk256, 0, stream>>>(aT, trT);
  k_wtrans<<<dim3(64, 128), blkT, 0, stream>>>(q12_w, wslot, 2048, 4096, 0);
  gemm_nt<1><<<dim3(64, 32), blk256, 0, stream>>>(trT, wslot, Qm, q12_b, 2048, 2048, 2048, 4096, 0, 0, 0, 1.f, 0);

  // seasonal -> K halves -> scores
  k_dseason<<<dim3(65536), blk256, 0, stream>>>(aT, seT);
  k_lambda<<<dim3(1), blk256, 0, stream>>>(lq1, lk1, lq2, lk2, lamp);

  k_wtrans<<<dim3(64, 64), blkT, 0, stream>>>(k12_w, wslot, 2048, 4096, 0);
  gemm_nt<1><<<dim3(64, 16), blk256, 0, stream>>>(seT, wslot, Kh, k12_b, 2048, 2048, 2048, 2048, 0, 0, 0, 1.f, 0);
  gemm_nt<0><<<dim3(4, 4, B_), blk256, 0, stream>>>(Qm, Kh, a1, nullptr, 2048, 4096, 2048, 512,
                                                    512L * 4096, 512L * 2048, 512L * 512, SCALE_F, 0);
  k_wtrans<<<dim3(64, 64), blkT, 0, stream>>>(k12_w, wslot, 2048, 4096, 2048);
  gemm_nt<1><<<dim3(64, 16), blk256, 0, stream>>>(seT, wslot, Kh, k12_b + 2048, 2048, 2048, 2048, 2048, 0, 0, 0, 1.f, 0);
  gemm_nt<0><<<dim3(4, 4, B_), blk256, 0, stream>>>(Qm + 2048, Kh, a2, nullptr, 2048, 4096, 2048, 512,
                                                    512L * 4096, 512L * 2048, 512L * 512, SCALE_F, 0);

  // softmax combine -> dmat, then P = d @ V (bf16 out)
  k_softmax<<<dim3(8192), blk256, 0, stream>>>(a1, a2, lamp, dmat);
  gemm_nt<3><<<dim3(4, 16, B_), blk256, 0, stream>>>(dmat, VT, Pm, nullptr, 512, 512, 512, 2048,
                                                     512L * 512, 2048L * 512, 512L * 2048, 1.f, 0);

  // post-attn fused norms
  k_postattn<<<dim3(8192), blk256, 0, stream>>>(Pm, xT, norm_w, ln_ff, attn, hbuf);

  // FFN: 4 chunks over H, accumulate f32 into d_out
  for (int c = 0; c < 4; ++c) {
    k_wtrans<<<dim3(64, 64), blkT, 0, stream>>>(ff_w1, wslot, 2048, 8192, 2048 * c);
    gemm_nt<2><<<dim3(64, 16), blk256, 0, stream>>>(hbuf, wslot, H1c, ff_b1 + 2048 * c,
                                                    2048, 2048, 2048, 2048, 0, 0, 0, 1.f, 0);
    k_wtrans<<<dim3(64, 64), blkT, 0, stream>>>(ff_w2 + (size_t)2048 * 2048 * c, wslot2, 2048, 2048, 0);
    gemm_nt<4><<<dim3(64, 16), blk256, 0, stream>>>(H1c, wslot2, ffoF, (c == 0) ? ff_b2 : nullptr,
                                                    2048, 2048, 2048, 2048, 0, 0, 0, 1.f, (c > 0) ? 1 : 0);
  }

  // sumT = attn + ffoF (both [B,C,S]); then out = x + sumT^T  (two passes: race-free vs d_out)
  k_combine<<<dim3(8192), blk256, 0, stream>>>(attn, ffoF, sumT);
  k_final<<<dim3(64, 16, B_), blkT, 0, stream>>>(x, sumT, out);
}